// Round 7
// baseline (11044.779 us; speedup 1.0000x reference)
//
#include <hip/hip_runtime.h>
#include <cstdint>

#define Bb 32
#define Cc 512
#define Nn 384
#define Vv 600
#define Ee 256
#define Dd 512
#define Tt 192
#define Ss 191
#define EOS_TOK 130
#define BD (Bb*Dd)          // 16384
#define NBLK 256
#define NTHR 512

// ---- ws layout (float offsets) ----
#define OFF_TOK   0                      // int tok[Ss*Bb]
#define OFF_SHIFT 8192                   // float shift[1]
#define OFF_WV    8256                   // Bb*Nn*Dd = 6291456
#define OFF_HXT   (OFF_WV + 6291456)     // 2 * 512*32 (double-buffered, [d][b])
#define OFF_XO    (OFF_HXT + 32768)      // 512*32 o_prev transposed [d][b]
#define OFF_CX    (OFF_XO + 16384)       // (unused now; cx lives in LDS)
#define OFF_DEN   (OFF_CX + 16384)       // denom[t][b] 191*32 (pad 8192)
#define OFF_Q     (OFF_DEN + 8192)       // q[b][d] 32*512
#define OFF_CTX   (OFF_Q + 16384)        // ctxT[c][b] 512*32
#define OFF_OBUF  (OFF_CTX + 16384)      // 192*BD; slot t+1 front 8192 doubles as embx[t]
#define OFF_BAR   (OFF_OBUF + 192*16384) // 1024 ints

#define LOGITS_SZ (Bb*Ss*Vv)  // 3667200
#define ALPHA_SZ  (Bb*Ss*Nn)  // 2347008

__device__ __forceinline__ float sigm_(float x) {
    float e = __expf(-x);
    return __builtin_amdgcn_rcpf(1.0f + e);
}
__device__ __forceinline__ float tanh_(float x) {
    float xc = fminf(15.0f, fmaxf(-15.0f, x));
    float e = __expf(2.0f * xc);
    return (e - 1.0f) * __builtin_amdgcn_rcpf(e + 1.0f);
}

// Write-through device store (sc1): value is at LLC once vmcnt retires, which
// __syncthreads guarantees before the barrier arrival RMW. So arrival needs
// NO release (no buffer_wbl2).
__device__ __forceinline__ void st_dev(float* p, float v) {
    __hip_atomic_store(p, v, __ATOMIC_RELAXED, __HIP_MEMORY_SCOPE_AGENT);
}

// Device barrier: relaxed arrival tree (16 leaves x 16 + root + gen), relaxed
// spin, then ONE ACQUIRE load at exit -> single buffer_inv per block per
// barrier. After it, plain cached loads see everything the other blocks
// wrote via st_dev / LLC atomics. (Round 6 instead made every cross-block
// read an LLC atomic: 176 serialized ~700-cyc round trips per thread per
// step -- that was the 27 us/step stall.)
__device__ __forceinline__ void gbar(int* bar, int ibar) {
    __syncthreads();
    if (threadIdx.x == 0) {
        int g = blockIdx.x >> 4;
        int a = __hip_atomic_fetch_add(&bar[g * 32], 1, __ATOMIC_RELAXED,
                                       __HIP_MEMORY_SCOPE_AGENT);
        if (a == ibar * 16 + 15) {
            int r = __hip_atomic_fetch_add(&bar[640], 1, __ATOMIC_RELAXED,
                                           __HIP_MEMORY_SCOPE_AGENT);
            if (r == ibar * 16 + 15)
                __hip_atomic_store(&bar[704], ibar + 1, __ATOMIC_RELAXED,
                                   __HIP_MEMORY_SCOPE_AGENT);
        }
        while (__hip_atomic_load(&bar[704], __ATOMIC_RELAXED,
                                 __HIP_MEMORY_SCOPE_AGENT) <= ibar)
            __builtin_amdgcn_s_sleep(2);
        (void)__hip_atomic_load(&bar[704], __ATOMIC_ACQUIRE,
                                __HIP_MEMORY_SCOPE_AGENT);
    }
    __syncthreads();
}

// S0: zero state/barriers/denoms, token sequence, exp-shift = sum|v|.
__global__ void k_setup(const int* __restrict__ tgt, const float* __restrict__ vv,
                        float* zbase, int* bar, int* tok, float* shiftbuf) {
    int gid = blockIdx.x * 256 + threadIdx.x;
    // zero hxT(32768)+xo(16384)+cx(16384)+den(8192) = 73728 floats
    for (int i = gid; i < 73728; i += 96 * 256) zbase[i] = 0.f;
    if (gid < 1024) bar[gid] = 0;
    if (blockIdx.x == 0) {
        __shared__ int is64;
        if (threadIdx.x == 0) {
            int a = 1;
            for (int k = 0; k < 32; ++k) if (tgt[2 * k + 1] != 0) a = 0;
            is64 = a;
        }
        __syncthreads();
        int b = threadIdx.x;
        if (b < Bb) {
            int fin = 0;
            tok[0 * Bb + b] = 0;
            for (int s = 1; s < Ss; ++s) {
                int li = b * Tt + s;
                int nt = is64 ? tgt[2 * li] : tgt[li];
                if (nt == EOS_TOK) fin = 1;
                tok[s * Bb + b] = fin ? 0 : nt;
            }
        }
    }
    if (blockIdx.x == 1) {
        __shared__ float sred[256];
        int tid = threadIdx.x;
        sred[tid] = fabsf(vv[tid]) + fabsf(vv[tid + 256]);
        __syncthreads();
        for (int s = 128; s > 0; s >>= 1) {
            if (tid < s) sred[tid] += sred[tid + s];
            __syncthreads();
        }
        if (tid == 0) shiftbuf[0] = sred[0];
    }
}

// S1: gather embeddings for all steps into obuf slot fronts: [t][k][b]
__global__ void k_embx(const float* __restrict__ emb, const int* __restrict__ tok,
                       float* __restrict__ obuf) {
    int i = blockIdx.x * 256 + threadIdx.x;   // over 191*8192
    if (i < Ss * 8192) {
        int t = i >> 13, e = i & 8191;
        int k = e >> 5, b = e & 31;
        obuf[(size_t)(t + 1) * BD + e] = emb[(size_t)tok[t * 32 + b] * Ee + k];
    }
}

// S2: Wv[b,n,d] = sum_c enc[b,n,c] * W_v[c,d]
__global__ void k_wv(const float* __restrict__ enc, const float* __restrict__ Wv_w,
                     float* __restrict__ Wv) {
    int b = blockIdx.x / 24, nt = blockIdx.x % 24, n0 = nt * 16;
    __shared__ float encL[16 * 512];
    for (int i = 0; i < 32; ++i) {
        int e = threadIdx.x + i * 256;
        int ni = e >> 9, c = e & 511;
        encL[e] = enc[((b * Nn) + (n0 + ni)) * Cc + c];
    }
    __syncthreads();
    int d0 = threadIdx.x, d1 = threadIdx.x + 256;
    float a0[16], a1[16];
#pragma unroll
    for (int i = 0; i < 16; ++i) { a0[i] = 0.f; a1[i] = 0.f; }
    for (int c = 0; c < 512; ++c) {
        float w0 = Wv_w[c * Dd + d0], w1 = Wv_w[c * Dd + d1];
#pragma unroll
        for (int i = 0; i < 16; ++i) {
            float ev = encL[i * 512 + c];
            a0[i] += ev * w0; a1[i] += ev * w1;
        }
    }
#pragma unroll
    for (int i = 0; i < 16; ++i) {
        Wv[((b * Nn) + (n0 + i)) * Dd + d0] = a0[i];
        Wv[((b * Nn) + (n0 + i)) * Dd + d1] = a1[i];
    }
}

// Persistent decode: 256 blocks x 512 threads, weights LDS-resident,
// 4 device barriers per step. Block bid owns output dims {2bid, 2bid+1}.
__global__ __launch_bounds__(NTHR) void k_decode(
    const float* __restrict__ enc, const float* __restrict__ W_ih,
    const float* __restrict__ b_ih, const float* __restrict__ W_hh,
    const float* __restrict__ b_hh, const float* __restrict__ W_h,
    const float* __restrict__ vv, const float* __restrict__ W_c,
    const float* __restrict__ b_c, const float* __restrict__ Wv,
    const float* __restrict__ shiftbuf,
    float* __restrict__ hxT, float* __restrict__ xo, float* __restrict__ cx_unused,
    float* __restrict__ den, float* __restrict__ q, float* __restrict__ ctxT,
    float* __restrict__ obuf, float* __restrict__ alpha_e, int* bar)
{
    __shared__ float Wg[1280 * 8];    // gates cols: [k][g*2+dd]   40960B
    __shared__ float Whx[512 * 2];    // W_h cols    [d][dd]        4096B
    __shared__ float Wc[1024 * 2];    // W_c cols    [k][dd]        8192B
    __shared__ float scratch[4096];   // phase-local               16384B
    __shared__ float cxL[64];         // block-private LSTM cell state

    const int tid = threadIdx.x, bid = blockIdx.x;
    const int lane = tid & 63;
    const int d0 = bid * 2;

    // ---- one-time weight staging into LDS (read-only, cached loads) ----
    for (int k = tid; k < 1280; k += NTHR) {
        const float* src = (k < 768) ? (W_ih + (size_t)k * 2048)
                                     : (W_hh + (size_t)(k - 768) * 2048);
#pragma unroll
        for (int g = 0; g < 4; ++g) {
            Wg[k * 8 + g * 2 + 0] = src[g * 512 + d0 + 0];
            Wg[k * 8 + g * 2 + 1] = src[g * 512 + d0 + 1];
        }
    }
    {
        int d = tid;  // NTHR == 512
        Whx[d * 2 + 0] = W_h[(size_t)d * 512 + d0 + 0];
        Whx[d * 2 + 1] = W_h[(size_t)d * 512 + d0 + 1];
    }
    for (int k = tid; k < 1024; k += NTHR) {
        Wc[k * 2 + 0] = W_c[(size_t)k * 512 + d0 + 0];
        Wc[k * 2 + 1] = W_c[(size_t)k * 512 + d0 + 1];
    }
    if (tid < 64) cxL[tid] = 0.f;
    float v8[8];
#pragma unroll
    for (int i = 0; i < 8; ++i) v8[i] = vv[lane + i * 64];
    const float SHIFT = shiftbuf[0];
    float bsum0 = 0.f, bsum1 = 0.f, bsum2 = 0.f, bsum3 = 0.f, bcv = 0.f;
    if (tid < 64) {
        int dd = tid >> 5;
        int d = d0 + dd;
        bsum0 = b_ih[0 * 512 + d] + b_hh[0 * 512 + d];
        bsum1 = b_ih[1 * 512 + d] + b_hh[1 * 512 + d];
        bsum2 = b_ih[2 * 512 + d] + b_hh[2 * 512 + d];
        bsum3 = b_ih[3 * 512 + d] + b_hh[3 * 512 + d];
        bcv = b_c[d];
    }
    __syncthreads();

    int ib = 0;
    for (int t = 0; t < Ss; ++t) {
        const int rd = t & 1, wr = 1 - rd;
        const float* hxT_rd = hxT + rd * 16384;
        float*       hxT_wr = hxT + wr * 16384;

        // ---------- Phase A: gates (full K) + LSTM ----------
        {
            const float* embx_t = obuf + (size_t)(t + 1) * BD;  // [k][b], k<256
            const float* xo2 = xo - 256 * 32;
            const float* hx2 = hxT_rd - 768 * 32;
            int b = tid & 31, ks = tid >> 5;       // 16 chunks of 80 k
            int k0 = ks * 80;
            float acc[8];
#pragma unroll
            for (int i = 0; i < 8; ++i) acc[i] = 0.f;
#pragma unroll 16
            for (int k = k0; k < k0 + 80; ++k) {
                const float* base = (k < 256) ? embx_t : ((k < 768) ? xo2 : hx2);
                float x = base[k * 32 + b];        // plain cached load (post-inv coherent)
                float4 wA = *(const float4*)&Wg[k * 8];
                float4 wB = *(const float4*)&Wg[k * 8 + 4];
                acc[0] += x * wA.x; acc[1] += x * wA.y; acc[2] += x * wA.z; acc[3] += x * wA.w;
                acc[4] += x * wB.x; acc[5] += x * wB.y; acc[6] += x * wB.z; acc[7] += x * wB.w;
            }
#pragma unroll
            for (int c = 0; c < 8; ++c) scratch[(ks * 8 + c) * 32 + b] = acc[c];
            __syncthreads();
            if (tid < 256) {
                int col = tid >> 5, b2 = tid & 31;
                float s = 0.f;
#pragma unroll
                for (int k2 = 0; k2 < 16; ++k2) s += scratch[(k2 * 8 + col) * 32 + b2];
                scratch[col * 32 + b2] = s;   // in-place: slot read only by this thread
            }
            __syncthreads();
            if (tid < 64) {
                int dd = tid >> 5, b2 = tid & 31;
                float gi = scratch[(0 * 2 + dd) * 32 + b2] + bsum0;
                float gf = scratch[(1 * 2 + dd) * 32 + b2] + bsum1;
                float gg = scratch[(2 * 2 + dd) * 32 + b2] + bsum2;
                float go = scratch[(3 * 2 + dd) * 32 + b2] + bsum3;
                float c = sigm_(gf) * cxL[tid] + sigm_(gi) * tanh_(gg);
                cxL[tid] = c;
                st_dev(&hxT_wr[(d0 + dd) * 32 + b2], sigm_(go) * tanh_(c));
            }
        }
        gbar(bar, ib++);

        // ---------- Phase C: q = hx @ W_h (2 cols) + zero ctxT slice ----------
        {
            if (tid < 64)
                st_dev(&ctxT[bid * 64 + tid], 0.f);
            int b = tid & 31, dc = tid >> 5;      // 16 chunks of 32 d
            float a0 = 0.f, a1 = 0.f;
#pragma unroll 16
            for (int d = dc * 32; d < dc * 32 + 32; ++d) {
                float h = hxT_wr[d * 32 + b];
                a0 += h * Whx[d * 2 + 0];
                a1 += h * Whx[d * 2 + 1];
            }
            scratch[(dc * 2 + 0) * 32 + b] = a0;
            scratch[(dc * 2 + 1) * 32 + b] = a1;
            __syncthreads();
            if (tid < 64) {
                int jj = tid >> 5, b2 = tid & 31;
                float s = 0.f;
#pragma unroll
                for (int d2 = 0; d2 < 16; ++d2) s += scratch[(d2 * 2 + jj) * 32 + b2];
                st_dev(&q[b2 * 512 + d0 + jj], s);
            }
        }
        gbar(bar, ib++);

        // ---------- Phase DE: scores + exp(shifted) + ctx atomics ----------
        {
            float* esc = scratch;            // 48 e-values
            int b = bid >> 3, n0 = (bid & 7) * 48;
            int w = tid >> 6;
            float q8[8];
#pragma unroll
            for (int i = 0; i < 8; ++i) q8[i] = q[b * 512 + lane + i * 64];
#pragma unroll
            for (int r = 0; r < 6; ++r) {
                int n = n0 + w * 6 + r;
                const float* wv = Wv + ((size_t)(b * Nn + n)) * 512;
                float s = 0.f;
#pragma unroll
                for (int i = 0; i < 8; ++i)
                    s += v8[i] * tanh_(q8[i] + wv[lane + i * 64]);
#pragma unroll
                for (int off = 32; off > 0; off >>= 1)
                    s += __shfl_down(s, off, 64);
                if (lane == 0) esc[w * 6 + r] = __expf(s - SHIFT);
            }
            __syncthreads();
            if (tid < 48)
                alpha_e[((size_t)b * Ss + t) * Nn + n0 + tid] = esc[tid];
            if (tid == 0) {
                float sd = 0.f;
                for (int i = 0; i < 48; ++i) sd += esc[i];
                atomicAdd(&den[t * 32 + b], sd);
            }
            int c = tid;
            float acc = 0.f;
#pragma unroll 8
            for (int i = 0; i < 48; ++i)
                acc += esc[i] * enc[((size_t)(b * Nn + n0 + i)) * 512 + c];
            atomicAdd(&ctxT[c * 32 + b], acc);
        }
        gbar(bar, ib++);

        // ---------- Phase F: o_t = tanh([hx|ctx/den] @ W_c + b_c) (2 cols) ----------
        {
            int b = tid & 31, kc = tid >> 5;      // 16 chunks of 64 k
            float dinv = 1.0f / den[t * 32 + b];
            float a0 = 0.f, a1 = 0.f;
            if (kc < 8) {
#pragma unroll 16
                for (int k = kc * 64; k < kc * 64 + 64; ++k) {
                    float x = hxT_wr[k * 32 + b];
                    a0 += x * Wc[k * 2 + 0]; a1 += x * Wc[k * 2 + 1];
                }
            } else {
#pragma unroll 16
                for (int k2 = (kc - 8) * 64; k2 < (kc - 8) * 64 + 64; ++k2) {
                    float x = ctxT[k2 * 32 + b];
                    a0 += x * Wc[(512 + k2) * 2 + 0]; a1 += x * Wc[(512 + k2) * 2 + 1];
                }
                a0 *= dinv; a1 *= dinv;   // normalize ctx half by softmax denom
            }
            scratch[(kc * 2 + 0) * 32 + b] = a0;
            scratch[(kc * 2 + 1) * 32 + b] = a1;
            __syncthreads();
            if (tid < 64) {
                int dd = tid >> 5, b2 = tid & 31;
                float s = bcv;
#pragma unroll
                for (int k2 = 0; k2 < 16; ++k2) s += scratch[(k2 * 2 + dd) * 32 + b2];
                float o = tanh_(s);
                st_dev(&xo[(d0 + dd) * 32 + b2], o);
                obuf[(size_t)(t + 1) * BD + b2 * 512 + d0 + dd] = o;  // read post-kernel
            }
        }
        gbar(bar, ib++);
    }
}

// Deferred logits GEMM.
__global__ void k_logits(const float* __restrict__ obuf, const float* __restrict__ W_out,
                         const float* __restrict__ b_out, float* __restrict__ out_logits) {
    int b = blockIdx.x / 24, tt = blockIdx.x % 24;
    int t0 = tt * 8;
    int tmax = min(8, Ss - t0);
    __shared__ float oL[8 * 512];
    int tid = threadIdx.x;
    for (int i = 0; i < 16; ++i) {
        int e = tid + i * 256;
        int ti = e >> 9, d = e & 511;
        oL[e] = (ti < tmax) ? obuf[(size_t)(t0 + ti + 1) * BD + b * Dd + d] : 0.f;
    }
    __syncthreads();
    int v0 = tid, v1 = tid + 256, v2 = tid + 512;
    bool h2 = (v2 < Vv);
    int v2c = h2 ? v2 : 0;
    float acc[3][8];
#pragma unroll
    for (int s = 0; s < 3; ++s)
#pragma unroll
        for (int ti = 0; ti < 8; ++ti) acc[s][ti] = 0.f;
    for (int d = 0; d < 512; ++d) {
        float w0 = W_out[d * Vv + v0];
        float w1 = W_out[d * Vv + v1];
        float w2 = W_out[d * Vv + v2c];
#pragma unroll
        for (int ti = 0; ti < 8; ++ti) {
            float o = oL[ti * 512 + d];
            acc[0][ti] += o * w0; acc[1][ti] += o * w1; acc[2][ti] += o * w2;
        }
    }
    for (int ti = 0; ti < tmax; ++ti) {
        size_t base = (size_t)b * (Ss * Vv) + (size_t)(t0 + ti) * Vv;
        out_logits[base + v0] = acc[0][ti] + b_out[v0];
        out_logits[base + v1] = acc[1][ti] + b_out[v1];
        if (h2) out_logits[base + v2] = acc[2][ti] + b_out[v2];
    }
}

// Normalize alphas: alpha /= denom[b,t]
__global__ void k_anorm(float* __restrict__ alph, const float* __restrict__ den) {
    int i = blockIdx.x * 256 + threadIdx.x;
    if (i < ALPHA_SZ) {
        int bt = i / Nn;
        int t = bt % Ss, b = bt / Ss;
        alph[i] = alph[i] / den[t * 32 + b];
    }
}

extern "C" void kernel_launch(void* const* d_in, const int* in_sizes, int n_in,
                              void* d_out, int out_size, void* d_ws, size_t ws_size,
                              hipStream_t stream) {
    const float* enc   = (const float*)d_in[0];
    const int*   tgt   = (const int*)d_in[1];
    const float* emb   = (const float*)d_in[2];
    const float* W_ih  = (const float*)d_in[3];
    const float* b_ih  = (const float*)d_in[4];
    const float* W_hh  = (const float*)d_in[5];
    const float* b_hh  = (const float*)d_in[6];
    const float* W_h   = (const float*)d_in[7];
    const float* W_v   = (const float*)d_in[8];
    const float* vv    = (const float*)d_in[9];
    const float* W_c   = (const float*)d_in[10];
    const float* b_c   = (const float*)d_in[11];
    const float* W_out = (const float*)d_in[12];
    const float* b_out = (const float*)d_in[13];

    float* wsf   = (float*)d_ws;
    int*   tok   = (int*)d_ws;
    float* shiftb= wsf + OFF_SHIFT;
    float* Wv    = wsf + OFF_WV;
    float* hxT   = wsf + OFF_HXT;
    float* xo    = wsf + OFF_XO;
    float* cx    = wsf + OFF_CX;
    float* den   = wsf + OFF_DEN;
    float* q     = wsf + OFF_Q;
    float* ctxT  = wsf + OFF_CTX;
    float* obuf  = wsf + OFF_OBUF;
    int*   bar   = (int*)(wsf + OFF_BAR);

    float* out_logits = (float*)d_out;
    float* out_alphas = (float*)d_out + LOGITS_SZ;

    k_setup<<<96, 256, 0, stream>>>(tgt, vv, hxT, bar, tok, shiftb);
    k_embx<<<(Ss * 8192 + 255) / 256, 256, 0, stream>>>(emb, tok, obuf);
    k_wv<<<768, 256, 0, stream>>>(enc, W_v, Wv);
    k_decode<<<NBLK, NTHR, 0, stream>>>(enc, W_ih, b_ih, W_hh, b_hh, W_h, vv,
                                        W_c, b_c, Wv, shiftb,
                                        hxT, xo, cx, den, q, ctxT, obuf,
                                        out_alphas, bar);
    k_logits<<<768, 256, 0, stream>>>(obuf, W_out, b_out, out_logits);
    k_anorm<<<(ALPHA_SZ + 255) / 256, 256, 0, stream>>>(out_alphas, den);
}

// Round 8
// 8392.152 us; speedup vs baseline: 1.3161x; 1.3161x over previous
//
#include <hip/hip_runtime.h>
#include <cstdint>

#define Bb 32
#define Cc 512
#define Nn 384
#define Vv 600
#define Ee 256
#define Dd 512
#define Tt 192
#define Ss 191
#define EOS_TOK 130
#define BD (Bb*Dd)          // 16384
#define NBLK 256
#define NTHR 512

// ---- ws layout (float offsets) ----
#define OFF_TOK   0                      // int tok[Ss*Bb]
#define OFF_SHIFT 8192                   // float shift[1]
#define OFF_WV    8256                   // Bb*Nn*Dd = 6291456
#define OFF_HXT   (OFF_WV + 6291456)     // 2 * 512*32 (double-buffered, [d][b])
#define OFF_XO    (OFF_HXT + 32768)      // 512*32 o_prev transposed [d][b]
#define OFF_CX    (OFF_XO + 16384)       // (unused; cx lives in LDS)
#define OFF_DEN   (OFF_CX + 16384)       // denom[t][b] 191*32 (pad 8192)
#define OFF_Q     (OFF_DEN + 8192)       // q[b][d] 32*512
#define OFF_CTX   (OFF_Q + 16384)        // ctxT[c][b] 512*32
#define OFF_OBUF  (OFF_CTX + 16384)      // 192*BD; slot t+1 front 8192 doubles as embx[t]
#define OFF_BAR   (OFF_OBUF + 192*16384) // flags[256*16] + gen

#define LOGITS_SZ (Bb*Ss*Vv)  // 3667200
#define ALPHA_SZ  (Bb*Ss*Nn)  // 2347008

__device__ __forceinline__ float sigm_(float x) {
    float e = __expf(-x);
    return __builtin_amdgcn_rcpf(1.0f + e);
}
__device__ __forceinline__ float tanh_(float x) {
    float xc = fminf(15.0f, fmaxf(-15.0f, x));
    float e = __expf(2.0f * xc);
    return (e - 1.0f) * __builtin_amdgcn_rcpf(e + 1.0f);
}

// Write-through device store (sc1): at LLC once vmcnt retires; __syncthreads
// drains vmcnt, so no release fence is ever needed.
__device__ __forceinline__ void st_dev(float* p, float v) {
    __hip_atomic_store(p, v, __ATOMIC_RELAXED, __HIP_MEMORY_SCOPE_AGENT);
}
// 8-byte coherent load (sc1 bypass, relaxed): halves the load count vs scalar.
// Safe: values are stable post-barrier, no tearing concern; offsets 8B-aligned.
__device__ __forceinline__ float2 ld2_dev(const float* p) {
    unsigned long long u = __hip_atomic_load((const unsigned long long*)p,
                                             __ATOMIC_RELAXED,
                                             __HIP_MEMORY_SCOPE_AGENT);
    float2 f;
    f.x = __uint_as_float((unsigned int)u);
    f.y = __uint_as_float((unsigned int)(u >> 32));
    return f;
}

// Flag-array device barrier: arrival = one independent sc1 store per block
// (flags 64B apart -> fully parallel, no RMW serialization). Block 0 wave 0
// polls all 256 flags (4/lane) and releases a gen flag. Monotonic targets.
__device__ __forceinline__ void gbar(int* flags, int* genp, int ibar) {
    __syncthreads();   // drains vmcnt: all sc1 data stores ack'd at LLC
    const int target = ibar + 1;
    if (threadIdx.x == 0)
        __hip_atomic_store(&flags[blockIdx.x * 16], target, __ATOMIC_RELAXED,
                           __HIP_MEMORY_SCOPE_AGENT);
    if (blockIdx.x == 0) {
        if (threadIdx.x < 64) {
            int l = threadIdx.x * 4;
            for (;;) {
                int f0 = __hip_atomic_load(&flags[(l + 0) * 16], __ATOMIC_RELAXED,
                                           __HIP_MEMORY_SCOPE_AGENT);
                int f1 = __hip_atomic_load(&flags[(l + 1) * 16], __ATOMIC_RELAXED,
                                           __HIP_MEMORY_SCOPE_AGENT);
                int f2 = __hip_atomic_load(&flags[(l + 2) * 16], __ATOMIC_RELAXED,
                                           __HIP_MEMORY_SCOPE_AGENT);
                int f3 = __hip_atomic_load(&flags[(l + 3) * 16], __ATOMIC_RELAXED,
                                           __HIP_MEMORY_SCOPE_AGENT);
                if (__all(f0 >= target && f1 >= target &&
                          f2 >= target && f3 >= target)) break;
                __builtin_amdgcn_s_sleep(1);
            }
            if (threadIdx.x == 0)
                __hip_atomic_store(genp, target, __ATOMIC_RELAXED,
                                   __HIP_MEMORY_SCOPE_AGENT);
        }
    } else if (threadIdx.x == 0) {
        while (__hip_atomic_load(genp, __ATOMIC_RELAXED,
                                 __HIP_MEMORY_SCOPE_AGENT) < target)
            __builtin_amdgcn_s_sleep(2);
    }
    __syncthreads();
}

// S0: zero state/flags/denoms, token sequence, exp-shift = sum|v|.
__global__ void k_setup(const int* __restrict__ tgt, const float* __restrict__ vv,
                        float* zbase, int* bar, int* tok, float* shiftbuf) {
    int gid = blockIdx.x * 256 + threadIdx.x;
    for (int i = gid; i < 73728; i += 96 * 256) zbase[i] = 0.f;
    if (gid < 4608) bar[gid] = 0;   // flags[4096] + gen line
    if (blockIdx.x == 0) {
        __shared__ int is64;
        if (threadIdx.x == 0) {
            int a = 1;
            for (int k = 0; k < 32; ++k) if (tgt[2 * k + 1] != 0) a = 0;
            is64 = a;
        }
        __syncthreads();
        int b = threadIdx.x;
        if (b < Bb) {
            int fin = 0;
            tok[0 * Bb + b] = 0;
            for (int s = 1; s < Ss; ++s) {
                int li = b * Tt + s;
                int nt = is64 ? tgt[2 * li] : tgt[li];
                if (nt == EOS_TOK) fin = 1;
                tok[s * Bb + b] = fin ? 0 : nt;
            }
        }
    }
    if (blockIdx.x == 1) {
        __shared__ float sred[256];
        int tid = threadIdx.x;
        sred[tid] = fabsf(vv[tid]) + fabsf(vv[tid + 256]);
        __syncthreads();
        for (int s = 128; s > 0; s >>= 1) {
            if (tid < s) sred[tid] += sred[tid + s];
            __syncthreads();
        }
        if (tid == 0) shiftbuf[0] = sred[0];
    }
}

// S1: gather embeddings for all steps into obuf slot fronts: [t][k][b]
__global__ void k_embx(const float* __restrict__ emb, const int* __restrict__ tok,
                       float* __restrict__ obuf) {
    int i = blockIdx.x * 256 + threadIdx.x;
    if (i < Ss * 8192) {
        int t = i >> 13, e = i & 8191;
        int k = e >> 5, b = e & 31;
        obuf[(size_t)(t + 1) * BD + e] = emb[(size_t)tok[t * 32 + b] * Ee + k];
    }
}

// S2: Wv[b,n,d] = sum_c enc[b,n,c] * W_v[c,d]
__global__ void k_wv(const float* __restrict__ enc, const float* __restrict__ Wv_w,
                     float* __restrict__ Wv) {
    int b = blockIdx.x / 24, nt = blockIdx.x % 24, n0 = nt * 16;
    __shared__ float encL[16 * 512];
    for (int i = 0; i < 32; ++i) {
        int e = threadIdx.x + i * 256;
        int ni = e >> 9, c = e & 511;
        encL[e] = enc[((b * Nn) + (n0 + ni)) * Cc + c];
    }
    __syncthreads();
    int d0 = threadIdx.x, d1 = threadIdx.x + 256;
    float a0[16], a1[16];
#pragma unroll
    for (int i = 0; i < 16; ++i) { a0[i] = 0.f; a1[i] = 0.f; }
    for (int c = 0; c < 512; ++c) {
        float w0 = Wv_w[c * Dd + d0], w1 = Wv_w[c * Dd + d1];
#pragma unroll
        for (int i = 0; i < 16; ++i) {
            float ev = encL[i * 512 + c];
            a0[i] += ev * w0; a1[i] += ev * w1;
        }
    }
#pragma unroll
    for (int i = 0; i < 16; ++i) {
        Wv[((b * Nn) + (n0 + i)) * Dd + d0] = a0[i];
        Wv[((b * Nn) + (n0 + i)) * Dd + d1] = a1[i];
    }
}

// Persistent decode: 256 blocks x 512 threads, weights LDS-resident,
// 4 flag-barriers per step. Block bid owns output dims {2bid, 2bid+1}.
__global__ __launch_bounds__(NTHR) void k_decode(
    const float* __restrict__ enc, const float* __restrict__ W_ih,
    const float* __restrict__ b_ih, const float* __restrict__ W_hh,
    const float* __restrict__ b_hh, const float* __restrict__ W_h,
    const float* __restrict__ vv, const float* __restrict__ W_c,
    const float* __restrict__ b_c, const float* __restrict__ Wv,
    const float* __restrict__ shiftbuf,
    float* __restrict__ hxT, float* __restrict__ xo,
    float* __restrict__ den, float* __restrict__ q, float* __restrict__ ctxT,
    float* __restrict__ obuf, float* __restrict__ alpha_e, int* bar)
{
    __shared__ float Wg[1280 * 8];    // gates cols [k][g*2+dd]    40960B
    __shared__ float Whx[512 * 2];    // W_h cols   [d][dd]         4096B
    __shared__ float Wc[1024 * 2];    // W_c cols   [k][dd]         8192B
    __shared__ float scratch[8192];   // phase-local               32768B
    __shared__ float cxL[64];         // block-private cell state

    int* flags = bar;
    int* genp  = bar + 4352;

    const int tid = threadIdx.x, bid = blockIdx.x;
    const int lane = tid & 63;
    const int d0 = bid * 2;
    const int bp = tid & 15;          // b-pair: b = 2bp, 2bp+1

    // ---- one-time weight staging into LDS ----
    for (int k = tid; k < 1280; k += NTHR) {
        const float* src = (k < 768) ? (W_ih + (size_t)k * 2048)
                                     : (W_hh + (size_t)(k - 768) * 2048);
#pragma unroll
        for (int g = 0; g < 4; ++g) {
            Wg[k * 8 + g * 2 + 0] = src[g * 512 + d0 + 0];
            Wg[k * 8 + g * 2 + 1] = src[g * 512 + d0 + 1];
        }
    }
    {
        int d = tid;  // NTHR == 512
        Whx[d * 2 + 0] = W_h[(size_t)d * 512 + d0 + 0];
        Whx[d * 2 + 1] = W_h[(size_t)d * 512 + d0 + 1];
    }
    for (int k = tid; k < 1024; k += NTHR) {
        Wc[k * 2 + 0] = W_c[(size_t)k * 512 + d0 + 0];
        Wc[k * 2 + 1] = W_c[(size_t)k * 512 + d0 + 1];
    }
    if (tid < 64) cxL[tid] = 0.f;
    float v8[8];
#pragma unroll
    for (int i = 0; i < 8; ++i) v8[i] = vv[lane * 8 + i];
    const float SHIFT = shiftbuf[0];
    float bsum0 = 0.f, bsum1 = 0.f, bsum2 = 0.f, bsum3 = 0.f, bcv = 0.f;
    if (tid < 64) {
        int dd = tid >> 5;
        int d = d0 + dd;
        bsum0 = b_ih[0 * 512 + d] + b_hh[0 * 512 + d];
        bsum1 = b_ih[1 * 512 + d] + b_hh[1 * 512 + d];
        bsum2 = b_ih[2 * 512 + d] + b_hh[2 * 512 + d];
        bsum3 = b_ih[3 * 512 + d] + b_hh[3 * 512 + d];
        bcv = b_c[d];
    }
    __syncthreads();

    int ib = 0;
    for (int t = 0; t < Ss; ++t) {
        const int rd = t & 1, wr = 1 - rd;
        const float* hxT_rd = hxT + rd * 16384;
        float*       hxT_wr = hxT + wr * 16384;

        // ---------- Phase A: gates (full K) + LSTM ----------
        {
            const float* embx_t = obuf + (size_t)(t + 1) * BD;  // [k][b], k<256
            const float* xo2 = xo - 256 * 32;
            const float* hx2 = hxT_rd - 768 * 32;
            int ks = tid >> 4;           // 32 k-chunks of 40
            int k0 = ks * 40;
            float ax[8], ay[8];
#pragma unroll
            for (int i = 0; i < 8; ++i) { ax[i] = 0.f; ay[i] = 0.f; }
#pragma unroll
            for (int kb = 0; kb < 5; ++kb) {
                int kbase = k0 + kb * 8;
                float2 xv[8];
#pragma unroll
                for (int j = 0; j < 8; ++j) {      // batch: 8 outstanding sc1 loads
                    int k = kbase + j;
                    const float* base = (k < 256) ? embx_t : ((k < 768) ? xo2 : hx2);
                    xv[j] = ld2_dev(base + k * 32 + 2 * bp);
                }
#pragma unroll
                for (int j = 0; j < 8; ++j) {      // then use
                    int k = kbase + j;
                    float4 wA = *(const float4*)&Wg[k * 8];
                    float4 wB = *(const float4*)&Wg[k * 8 + 4];
                    ax[0] += xv[j].x * wA.x; ay[0] += xv[j].y * wA.x;
                    ax[1] += xv[j].x * wA.y; ay[1] += xv[j].y * wA.y;
                    ax[2] += xv[j].x * wA.z; ay[2] += xv[j].y * wA.z;
                    ax[3] += xv[j].x * wA.w; ay[3] += xv[j].y * wA.w;
                    ax[4] += xv[j].x * wB.x; ay[4] += xv[j].y * wB.x;
                    ax[5] += xv[j].x * wB.y; ay[5] += xv[j].y * wB.y;
                    ax[6] += xv[j].x * wB.z; ay[6] += xv[j].y * wB.z;
                    ax[7] += xv[j].x * wB.w; ay[7] += xv[j].y * wB.w;
                }
            }
#pragma unroll
            for (int c = 0; c < 8; ++c) {
                scratch[(ks * 8 + c) * 32 + 2 * bp]     = ax[c];
                scratch[(ks * 8 + c) * 32 + 2 * bp + 1] = ay[c];
            }
            __syncthreads();
            if (tid < 256) {
                int col = tid >> 5, b2 = tid & 31;
                float s = 0.f;
#pragma unroll
                for (int k2 = 0; k2 < 32; ++k2) s += scratch[(k2 * 8 + col) * 32 + b2];
                scratch[col * 32 + b2] = s;   // in-place: slot read only by this thread
            }
            __syncthreads();
            if (tid < 64) {
                int dd = tid >> 5, b2 = tid & 31;
                float gi = scratch[(0 * 2 + dd) * 32 + b2] + bsum0;
                float gf = scratch[(1 * 2 + dd) * 32 + b2] + bsum1;
                float gg = scratch[(2 * 2 + dd) * 32 + b2] + bsum2;
                float go = scratch[(3 * 2 + dd) * 32 + b2] + bsum3;
                float c = sigm_(gf) * cxL[tid] + sigm_(gi) * tanh_(gg);
                cxL[tid] = c;
                st_dev(&hxT_wr[(d0 + dd) * 32 + b2], sigm_(go) * tanh_(c));
            }
        }
        gbar(flags, genp, ib++);

        // ---------- Phase C: q = hx @ W_h (2 cols) + zero ctxT slice ----------
        {
            if (tid < 64)
                st_dev(&ctxT[bid * 64 + tid], 0.f);
            int dc = tid >> 4;            // 32 d-chunks of 16
            int dbase = dc * 16;
            float a00 = 0.f, a01 = 0.f, a10 = 0.f, a11 = 0.f;  // [col][b-in-pair]
#pragma unroll
            for (int db = 0; db < 2; ++db) {
                float2 hv[8];
#pragma unroll
                for (int j = 0; j < 8; ++j)
                    hv[j] = ld2_dev(hxT_wr + (dbase + db * 8 + j) * 32 + 2 * bp);
#pragma unroll
                for (int j = 0; j < 8; ++j) {
                    int d = dbase + db * 8 + j;
                    float w0 = Whx[d * 2 + 0], w1 = Whx[d * 2 + 1];
                    a00 += hv[j].x * w0; a10 += hv[j].y * w0;
                    a01 += hv[j].x * w1; a11 += hv[j].y * w1;
                }
            }
            scratch[(dc * 2 + 0) * 32 + 2 * bp]     = a00;
            scratch[(dc * 2 + 0) * 32 + 2 * bp + 1] = a10;
            scratch[(dc * 2 + 1) * 32 + 2 * bp]     = a01;
            scratch[(dc * 2 + 1) * 32 + 2 * bp + 1] = a11;
            __syncthreads();
            if (tid < 64) {
                int jj = tid >> 5, b2 = tid & 31;
                float s = 0.f;
#pragma unroll
                for (int d2 = 0; d2 < 32; ++d2) s += scratch[(d2 * 2 + jj) * 32 + b2];
                st_dev(&q[b2 * 512 + d0 + jj], s);
            }
        }
        gbar(flags, genp, ib++);

        // ---------- Phase DE: scores + exp(shifted) + ctx atomics ----------
        {
            float* esc = scratch;            // 48 e-values
            int b = bid >> 3, n0 = (bid & 7) * 48;
            int w = tid >> 6;
            float q8[8];
#pragma unroll
            for (int j = 0; j < 4; ++j) {    // 4 batched sc1 float2 loads
                float2 qv = ld2_dev(&q[b * 512 + lane * 8 + 2 * j]);
                q8[2 * j] = qv.x; q8[2 * j + 1] = qv.y;
            }
#pragma unroll
            for (int r = 0; r < 6; ++r) {
                int n = n0 + w * 6 + r;
                const float* wv = Wv + ((size_t)(b * Nn + n)) * 512 + lane * 8;
                float4 wa = *(const float4*)wv;
                float4 wb = *(const float4*)(wv + 4);
                float s = v8[0] * tanh_(q8[0] + wa.x) + v8[1] * tanh_(q8[1] + wa.y)
                        + v8[2] * tanh_(q8[2] + wa.z) + v8[3] * tanh_(q8[3] + wa.w)
                        + v8[4] * tanh_(q8[4] + wb.x) + v8[5] * tanh_(q8[5] + wb.y)
                        + v8[6] * tanh_(q8[6] + wb.z) + v8[7] * tanh_(q8[7] + wb.w);
#pragma unroll
                for (int off = 32; off > 0; off >>= 1)
                    s += __shfl_down(s, off, 64);
                if (lane == 0) esc[w * 6 + r] = __expf(s - SHIFT);
            }
            __syncthreads();
            if (tid < 48)
                alpha_e[((size_t)b * Ss + t) * Nn + n0 + tid] = esc[tid];
            if (tid == 0) {
                float sd = 0.f;
                for (int i = 0; i < 48; ++i) sd += esc[i];
                atomicAdd(&den[t * 32 + b], sd);
            }
            int c = tid;
            float acc = 0.f;
#pragma unroll 8
            for (int i = 0; i < 48; ++i)
                acc += esc[i] * enc[((size_t)(b * Nn + n0 + i)) * 512 + c];  // read-only, cached
            atomicAdd(&ctxT[c * 32 + b], acc);
        }
        gbar(flags, genp, ib++);

        // ---------- Phase F: o_t = tanh([hx|ctx/den] @ W_c + b_c) (2 cols) ----------
        {
            int kc = tid >> 4;            // 32 k-chunks of 32 (16 hx + 16 ctx)
            float2 dp = ld2_dev(&den[t * 32 + 2 * bp]);
            float dx = 1.0f / dp.x, dy = 1.0f / dp.y;
            const float* src = (kc < 16) ? hxT_wr : (ctxT - 512 * 32);
            int kb0 = kc * 32;
            float a00 = 0.f, a01 = 0.f, a10 = 0.f, a11 = 0.f;
#pragma unroll
            for (int kb = 0; kb < 4; ++kb) {
                float2 xv[8];
#pragma unroll
                for (int j = 0; j < 8; ++j)
                    xv[j] = ld2_dev(src + (kb0 + kb * 8 + j) * 32 + 2 * bp);
#pragma unroll
                for (int j = 0; j < 8; ++j) {
                    int k = kb0 + kb * 8 + j;
                    float w0 = Wc[k * 2 + 0], w1 = Wc[k * 2 + 1];
                    a00 += xv[j].x * w0; a10 += xv[j].y * w0;
                    a01 += xv[j].x * w1; a11 += xv[j].y * w1;
                }
            }
            if (kc >= 16) { a00 *= dx; a01 *= dx; a10 *= dy; a11 *= dy; }
            scratch[(kc * 2 + 0) * 32 + 2 * bp]     = a00;
            scratch[(kc * 2 + 0) * 32 + 2 * bp + 1] = a10;
            scratch[(kc * 2 + 1) * 32 + 2 * bp]     = a01;
            scratch[(kc * 2 + 1) * 32 + 2 * bp + 1] = a11;
            __syncthreads();
            if (tid < 64) {
                int dd = tid >> 5, b2 = tid & 31;
                float s = bcv;
#pragma unroll
                for (int k2 = 0; k2 < 32; ++k2) s += scratch[(k2 * 2 + dd) * 32 + b2];
                float o = tanh_(s);
                st_dev(&xo[(d0 + dd) * 32 + b2], o);
                obuf[(size_t)(t + 1) * BD + b2 * 512 + d0 + dd] = o;  // read post-kernel
            }
        }
        gbar(flags, genp, ib++);
    }
}

// Deferred logits GEMM.
__global__ void k_logits(const float* __restrict__ obuf, const float* __restrict__ W_out,
                         const float* __restrict__ b_out, float* __restrict__ out_logits) {
    int b = blockIdx.x / 24, tt = blockIdx.x % 24;
    int t0 = tt * 8;
    int tmax = min(8, Ss - t0);
    __shared__ float oL[8 * 512];
    int tid = threadIdx.x;
    for (int i = 0; i < 16; ++i) {
        int e = tid + i * 256;
        int ti = e >> 9, d = e & 511;
        oL[e] = (ti < tmax) ? obuf[(size_t)(t0 + ti + 1) * BD + b * Dd + d] : 0.f;
    }
    __syncthreads();
    int v0 = tid, v1 = tid + 256, v2 = tid + 512;
    bool h2 = (v2 < Vv);
    int v2c = h2 ? v2 : 0;
    float acc[3][8];
#pragma unroll
    for (int s = 0; s < 3; ++s)
#pragma unroll
        for (int ti = 0; ti < 8; ++ti) acc[s][ti] = 0.f;
    for (int d = 0; d < 512; ++d) {
        float w0 = W_out[d * Vv + v0];
        float w1 = W_out[d * Vv + v1];
        float w2 = W_out[d * Vv + v2c];
#pragma unroll
        for (int ti = 0; ti < 8; ++ti) {
            float o = oL[ti * 512 + d];
            acc[0][ti] += o * w0; acc[1][ti] += o * w1; acc[2][ti] += o * w2;
        }
    }
    for (int ti = 0; ti < tmax; ++ti) {
        size_t base = (size_t)b * (Ss * Vv) + (size_t)(t0 + ti) * Vv;
        out_logits[base + v0] = acc[0][ti] + b_out[v0];
        out_logits[base + v1] = acc[1][ti] + b_out[v1];
        if (h2) out_logits[base + v2] = acc[2][ti] + b_out[v2];
    }
}

// Normalize alphas: alpha /= denom[b,t]
__global__ void k_anorm(float* __restrict__ alph, const float* __restrict__ den) {
    int i = blockIdx.x * 256 + threadIdx.x;
    if (i < ALPHA_SZ) {
        int bt = i / Nn;
        int t = bt % Ss, b = bt / Ss;
        alph[i] = alph[i] / den[t * 32 + b];
    }
}

extern "C" void kernel_launch(void* const* d_in, const int* in_sizes, int n_in,
                              void* d_out, int out_size, void* d_ws, size_t ws_size,
                              hipStream_t stream) {
    const float* enc   = (const float*)d_in[0];
    const int*   tgt   = (const int*)d_in[1];
    const float* emb   = (const float*)d_in[2];
    const float* W_ih  = (const float*)d_in[3];
    const float* b_ih  = (const float*)d_in[4];
    const float* W_hh  = (const float*)d_in[5];
    const float* b_hh  = (const float*)d_in[6];
    const float* W_h   = (const float*)d_in[7];
    const float* W_v   = (const float*)d_in[8];
    const float* vv    = (const float*)d_in[9];
    const float* W_c   = (const float*)d_in[10];
    const float* b_c   = (const float*)d_in[11];
    const float* W_out = (const float*)d_in[12];
    const float* b_out = (const float*)d_in[13];

    float* wsf   = (float*)d_ws;
    int*   tok   = (int*)d_ws;
    float* shiftb= wsf + OFF_SHIFT;
    float* Wv    = wsf + OFF_WV;
    float* hxT   = wsf + OFF_HXT;
    float* xo    = wsf + OFF_XO;
    float* den   = wsf + OFF_DEN;
    float* q     = wsf + OFF_Q;
    float* ctxT  = wsf + OFF_CTX;
    float* obuf  = wsf + OFF_OBUF;
    int*   bar   = (int*)(wsf + OFF_BAR);

    float* out_logits = (float*)d_out;
    float* out_alphas = (float*)d_out + LOGITS_SZ;

    k_setup<<<96, 256, 0, stream>>>(tgt, vv, hxT, bar, tok, shiftb);
    k_embx<<<(Ss * 8192 + 255) / 256, 256, 0, stream>>>(emb, tok, obuf);
    k_wv<<<768, 256, 0, stream>>>(enc, W_v, Wv);
    k_decode<<<NBLK, NTHR, 0, stream>>>(enc, W_ih, b_ih, W_hh, b_hh, W_h, vv,
                                        W_c, b_c, Wv, shiftb,
                                        hxT, xo, den, q, ctxT, obuf,
                                        out_alphas, bar);
    k_logits<<<768, 256, 0, stream>>>(obuf, W_out, b_out, out_logits);
    k_anorm<<<(ALPHA_SZ + 255) / 256, 256, 0, stream>>>(out_alphas, den);
}